// Round 16
// baseline (164.397 us; speedup 1.0000x reference)
//
#include <hip/hip_runtime.h>
#include <math.h>

#define NN 100000
#define NE 1600000
#define F_IN 128
#define HID 64
#define OUTF 40
#define NBKT 391     // node buckets of 256 nodes
#define BCAPB 5120   // per-bucket capacity (mean 4096, +16 sigma)
#define TILE 8192    // edges per k_bucket block
#define NTILES 196   // ceil(NE/TILE)

typedef unsigned short u16;
typedef __attribute__((ext_vector_type(8))) __bf16 bf16x8;
typedef __attribute__((ext_vector_type(4))) float f32x4;

__device__ __forceinline__ u16 f2bf(float f) {  // RNE
    unsigned int x = __float_as_uint(f);
    return (u16)((x + 0x7fffu + ((x >> 16) & 1u)) >> 16);
}

// unpack int4 = 8 bf16, add into acc[8] (rows are pre-scaled by dinv -> pure add)
__device__ __forceinline__ void add8(const int4 v, float* acc) {
    acc[0] += __uint_as_float(((unsigned)v.x) << 16);
    acc[1] += __uint_as_float(v.x & 0xffff0000u);
    acc[2] += __uint_as_float(((unsigned)v.y) << 16);
    acc[3] += __uint_as_float(v.y & 0xffff0000u);
    acc[4] += __uint_as_float(((unsigned)v.z) << 16);
    acc[5] += __uint_as_float(v.z & 0xffff0000u);
    acc[6] += __uint_as_float(((unsigned)v.w) << 16);
    acc[7] += __uint_as_float(v.w & 0xffff0000u);
}

// ---------------- CSR build: LDS counting sort ----------------
__global__ void k_zero(int* bcnt) {
    int i = threadIdx.x;
    if (i < NBKT) bcnt[i] = 0;
}

__launch_bounds__(512)
__global__ void k_bucket(const int* __restrict__ ei, int* __restrict__ bcnt,
                         int* __restrict__ bkt) {
    __shared__ int hist[NBKT], goff[NBKT], cur[NBKT];
    __shared__ int ss[512];
    __shared__ int stage[TILE];
    int t = threadIdx.x;
    int e0 = blockIdx.x * TILE;
    int ecnt = min(TILE, NE - e0);
    if (t < NBKT) hist[t] = 0;
    __syncthreads();
    for (int i = t; i < ecnt; i += 512)
        atomicAdd(&hist[ei[NE + e0 + i] >> 8], 1);
    __syncthreads();
    // parallel exclusive scan over 391 bucket counts
    ss[t] = (t < NBKT) ? hist[t] : 0;
    __syncthreads();
    for (int o = 1; o < 512; o <<= 1) {
        int add = (t >= o) ? ss[t - o] : 0;
        __syncthreads();
        ss[t] += add;
        __syncthreads();
    }
    if (t < NBKT) cur[t] = ss[t] - hist[t];  // exclusive prefix
    if (t < NBKT) goff[t] = atomicAdd(&bcnt[t], hist[t]);
    __syncthreads();
    for (int i = t; i < ecnt; i += 512) {
        int c = ei[NE + e0 + i];
        int r = ei[e0 + i];
        int pos = atomicAdd(&cur[c >> 8], 1);
        stage[pos] = ((c & 255) << 17) | r;
    }
    __syncthreads();
    int wv = t >> 6, ln = t & 63;
    for (int b = wv; b < NBKT; b += 8) {
        int cnt = hist[b];
        int lo = cur[b] - cnt;
        int gb = b * BCAPB + goff[b];
        for (int i = ln; i < cnt; i += 64)
            bkt[gb + i] = stage[lo + i];
    }
}

// One block per bucket. Computes its own base = prefix(bcnt[0..b)) via
// masked block-reduce (R15: k_scanb kernel folded in, one fewer launch).
__launch_bounds__(256)
__global__ void k_csr(const int* __restrict__ bcnt, const int* __restrict__ bkt,
                      float* __restrict__ dinv, int* __restrict__ cursor,
                      int* __restrict__ eidx) {
    __shared__ int hist[256], loff[256], cur[256], sscan[256];
    __shared__ int stage[BCAPB];
    int t = threadIdx.x;
    int b = blockIdx.x;
    // base = sum of bcnt[0..b)
    int v0 = (t < b) ? bcnt[t] : 0;
    int v1 = (t + 256 < b) ? bcnt[t + 256] : 0;
    sscan[t] = v0 + v1;
    __syncthreads();
    for (int o = 128; o > 0; o >>= 1) {
        if (t < o) sscan[t] += sscan[t + o];
        __syncthreads();
    }
    int base = sscan[0];
    int cnt = bcnt[b];
    const int* bp = bkt + b * BCAPB;
    hist[t] = 0;
    __syncthreads();
    for (int i = t; i < cnt; i += 256)
        atomicAdd(&hist[bp[i] >> 17], 1);
    __syncthreads();
    int n = b * 256 + t;
    int d = hist[t];
    if (n < NN) dinv[n] = rsqrtf((float)(d + 1));  // +1 self-loop
    sscan[t] = d;
    __syncthreads();
    for (int o = 1; o < 256; o <<= 1) {
        int add = (t >= o) ? sscan[t - o] : 0;
        __syncthreads();
        sscan[t] += add;
        __syncthreads();
    }
    loff[t] = sscan[t] - d;
    cur[t] = 0;
    if (n < NN) cursor[n] = base + sscan[t];  // rowoff[n+1]
    __syncthreads();
    for (int i = t; i < cnt; i += 256) {
        int v = bp[i];
        int pos = loff[v >> 17] + atomicAdd(&cur[v >> 17], 1);
        stage[pos] = v & 0x1FFFF;
    }
    __syncthreads();
    for (int i = t; i < cnt; i += 256)
        eidx[base + i] = stage[i];
}

// ---------------- GEMM1 (MFMA bf16): h1' = bf16((x @ W1) * dinv[row]) ----------------
__launch_bounds__(256)
__global__ void k_gemm1(const float* __restrict__ x, const float* __restrict__ W1,
                        const float* __restrict__ dinv, u16* __restrict__ h1) {
    __shared__ u16 Xs[64][136];   // bf16 x-tile, +8 pad
    __shared__ u16 Wt[64][136];   // bf16 W1^T [col][k]
    int t = threadIdx.x;
    int row0 = blockIdx.x * 64;

    for (int idx = t; idx < F_IN * HID; idx += 256)
        Wt[idx & 63][idx >> 6] = f2bf(W1[idx]);
#pragma unroll
    for (int i = 0; i < 8; i++) {
        int idx4 = t + 256 * i;
        int r = idx4 >> 5;
        int c4 = (idx4 & 31) << 2;
        int gr = row0 + r;
        if (gr >= NN) gr = NN - 1;
        float4 v = *(const float4*)&x[gr * F_IN + c4];
        ushort4 o;
        o.x = f2bf(v.x); o.y = f2bf(v.y); o.z = f2bf(v.z); o.w = f2bf(v.w);
        *(ushort4*)&Xs[r][c4] = o;
    }
    __syncthreads();

    int wave = t >> 6, lane = t & 63;
    int rloc = lane & 15;
    int koct = (lane >> 4) * 8;
    int wrow = wave * 16;

    f32x4 acc0 = {}, acc1 = {}, acc2 = {}, acc3 = {};
#pragma unroll
    for (int s = 0; s < 4; s++) {
        int k0 = s * 32 + koct;
        bf16x8 a = *(const bf16x8*)&Xs[wrow + rloc][k0];
        bf16x8 b0 = *(const bf16x8*)&Wt[rloc][k0];
        bf16x8 b1 = *(const bf16x8*)&Wt[16 + rloc][k0];
        bf16x8 b2 = *(const bf16x8*)&Wt[32 + rloc][k0];
        bf16x8 b3 = *(const bf16x8*)&Wt[48 + rloc][k0];
        acc0 = __builtin_amdgcn_mfma_f32_16x16x32_bf16(a, b0, acc0, 0, 0, 0);
        acc1 = __builtin_amdgcn_mfma_f32_16x16x32_bf16(a, b1, acc1, 0, 0, 0);
        acc2 = __builtin_amdgcn_mfma_f32_16x16x32_bf16(a, b2, acc2, 0, 0, 0);
        acc3 = __builtin_amdgcn_mfma_f32_16x16x32_bf16(a, b3, acc3, 0, 0, 0);
    }

    int rq = (lane >> 4) * 4;
#pragma unroll
    for (int i = 0; i < 4; i++) {
        int gr = row0 + wrow + rq + i;
        if (gr < NN) {
            float dn = dinv[gr];
            size_t base = (size_t)gr * HID + rloc;
            h1[base]      = f2bf(acc0[i] * dn);
            h1[base + 16] = f2bf(acc1[i] * dn);
            h1[base + 32] = f2bf(acc2[i] * dn);
            h1[base + 48] = f2bf(acc3[i] * dn);
        }
    }
}

// ---------------- aggregation: TWO nodes per wave, 4-deep load issue ----------------
// (R15: deg~16 -> kmax=4; issuing all 4 k-steps at once puts a whole node's
// gathers in one memory round trip. 4 int4 temps, 2 acc sets, ~48 VGPR.)
template <bool RELU_BIAS>
__global__ void k_agg(const int* __restrict__ cursor, const int* __restrict__ eidx,
                      const float* __restrict__ dinv, const u16* __restrict__ h,
                      const float* __restrict__ bias, u16* __restrict__ outp) {
    int lane = threadIdx.x & 63;
    int wid = (blockIdx.x * blockDim.x + threadIdx.x) >> 6;
    int half = lane >> 5;
    int li = lane & 31;
    int n = wid * 2 + half;            // NN even, grid exact -> always < NN
    int eg = (lane >> 3) & 3;          // edge group 0..3 within half
    int fo = (lane & 7) * 8;           // 8 bf16 per lane
    int hbase = lane & 32;             // shfl base for this half
    int end = cursor[n];
    int start = (n == 0) ? 0 : cursor[n - 1];
    int deg = end - start;
    int degw = max(deg, __shfl_xor(deg, 32, 64));  // uniform loop bound

    float acc[8] = {}, acc2[8] = {};
    if (eg == 0) {  // self-loop row
        int4 hv = *(const int4*)&h[n * HID + fo];
        add8(hv, acc);
    }
    for (int c0 = 0; c0 < degw; c0 += 32) {
        int m = min(32, deg - c0);
        int mw = min(32, degw - c0);
        int sidx = (li < m) ? eidx[start + c0 + li] : 0;
        int kmax = (mw + 3) >> 2;
        int k = 0;
        for (; k + 4 <= kmax; k += 4) {
            int e0 = eg + (k << 2), e1 = e0 + 4, e2 = e0 + 8, e3 = e0 + 12;
            int s0 = __shfl(sidx, hbase + e0, 64);
            int s1 = __shfl(sidx, hbase + e1, 64);
            int s2 = __shfl(sidx, hbase + e2, 64);
            int s3 = __shfl(sidx, hbase + e3, 64);
            bool g0 = e0 < m, g1 = e1 < m, g2 = e2 < m, g3 = e3 < m;
            int4 a0, a1, a2, a3;
            if (g0) a0 = *(const int4*)&h[s0 * HID + fo];
            if (g1) a1 = *(const int4*)&h[s1 * HID + fo];
            if (g2) a2 = *(const int4*)&h[s2 * HID + fo];
            if (g3) a3 = *(const int4*)&h[s3 * HID + fo];
            if (g0) add8(a0, acc);
            if (g1) add8(a1, acc2);
            if (g2) add8(a2, acc);
            if (g3) add8(a3, acc2);
        }
        for (; k + 2 <= kmax; k += 2) {
            int e0 = eg + (k << 2), e1 = e0 + 4;
            int s0 = __shfl(sidx, hbase + e0, 64);
            int s1 = __shfl(sidx, hbase + e1, 64);
            if (e0 < m) { int4 a = *(const int4*)&h[s0 * HID + fo]; add8(a, acc); }
            if (e1 < m) { int4 b = *(const int4*)&h[s1 * HID + fo]; add8(b, acc2); }
        }
        if (k < kmax) {
            int e0 = eg + (k << 2);
            int s0 = __shfl(sidx, hbase + e0, 64);
            if (e0 < m) { int4 a = *(const int4*)&h[s0 * HID + fo]; add8(a, acc); }
        }
    }
#pragma unroll
    for (int i = 0; i < 8; i++) acc[i] += acc2[i];

    // reduce across the 4 edge groups of each half (lane bits 3,4)
#pragma unroll
    for (int o = 8; o <= 16; o <<= 1) {
#pragma unroll
        for (int i = 0; i < 8; i++) acc[i] += __shfl_xor(acc[i], o, 64);
    }
    if (eg == 0) {
        float dn = dinv[n];
        if (RELU_BIAS) {
#pragma unroll
            for (int i = 0; i < 8; i++)
                acc[i] = fmaxf(dn * acc[i] + bias[fo + i], 0.f) * dn;
        } else {
#pragma unroll
            for (int i = 0; i < 8; i++) acc[i] *= dn;
        }
        int4 o;
        o.x = (int)f2bf(acc[0]) | ((int)f2bf(acc[1]) << 16);
        o.y = (int)f2bf(acc[2]) | ((int)f2bf(acc[3]) << 16);
        o.z = (int)f2bf(acc[4]) | ((int)f2bf(acc[5]) << 16);
        o.w = (int)f2bf(acc[6]) | ((int)f2bf(acc[7]) << 16);
        *(int4*)&outp[(size_t)n * HID + fo] = o;
    }
}

// ---------------- GEMM2 (bf16 s) + bias + log_softmax fused ----------------
__launch_bounds__(320)
__global__ void k_gemm2(const u16* __restrict__ s_in, const float* __restrict__ W2,
                        const float* __restrict__ b2, float* __restrict__ outb) {
    __shared__ float As[128][68];   // staging; later reused as Os[40][132]
    __shared__ float Ws[64][40];
    __shared__ float rowm[128], rowls[128];
    int t = threadIdx.x;
    int row0 = blockIdx.x * 128;

    for (int i = t; i < 64 * 40; i += 320) Ws[i / 40][i % 40] = W2[i];

    for (int idx8 = t; idx8 < 1024; idx8 += 320) {
        int r = idx8 >> 3, k8 = (idx8 & 7) << 3;
        int gr = row0 + r;
        if (gr >= NN) gr = NN - 1;
        int4 v = *(const int4*)&s_in[(size_t)gr * HID + k8];
        float* dst = &As[r][k8];
        dst[0] = __uint_as_float(((unsigned)v.x) << 16);
        dst[1] = __uint_as_float(v.x & 0xffff0000u);
        dst[2] = __uint_as_float(((unsigned)v.y) << 16);
        dst[3] = __uint_as_float(v.y & 0xffff0000u);
        dst[4] = __uint_as_float(((unsigned)v.z) << 16);
        dst[5] = __uint_as_float(v.z & 0xffff0000u);
        dst[6] = __uint_as_float(((unsigned)v.w) << 16);
        dst[7] = __uint_as_float(v.w & 0xffff0000u);
    }
    __syncthreads();

    int tx = t % 10, ty = t / 10;
    int cb = tx * 4, rb = ty * 4;
    float acc[4][4] = {};
#pragma unroll 2   // capped: full unroll spills (R1)
    for (int k = 0; k < HID; k += 4) {
        float4 xv[4], wv[4];
#pragma unroll
        for (int i = 0; i < 4; i++) xv[i] = *(const float4*)&As[rb + i][k];
#pragma unroll
        for (int kk = 0; kk < 4; kk++) wv[kk] = *(const float4*)&Ws[k + kk][cb];
#pragma unroll
        for (int i = 0; i < 4; i++) {
            const float* xp = (const float*)&xv[i];
#pragma unroll
            for (int kk = 0; kk < 4; kk++) {
                acc[i][0] += xp[kk] * wv[kk].x;
                acc[i][1] += xp[kk] * wv[kk].y;
                acc[i][2] += xp[kk] * wv[kk].z;
                acc[i][3] += xp[kk] * wv[kk].w;
            }
        }
    }
    float4 bb = *(const float4*)&b2[cb];
#pragma unroll
    for (int i = 0; i < 4; i++) {
        acc[i][0] += bb.x; acc[i][1] += bb.y;
        acc[i][2] += bb.z; acc[i][3] += bb.w;
    }

    __syncthreads();  // all As reads done; reuse as Os[40][132]
    float* Os = &As[0][0];
#pragma unroll
    for (int i = 0; i < 4; i++) {
        int row = rb + i;
        Os[(cb + 0) * 132 + row] = acc[i][0];
        Os[(cb + 1) * 132 + row] = acc[i][1];
        Os[(cb + 2) * 132 + row] = acc[i][2];
        Os[(cb + 3) * 132 + row] = acc[i][3];
    }
    __syncthreads();
    if (t < 128) {
        float m = -INFINITY;
        for (int c = 0; c < OUTF; c++) m = fmaxf(m, Os[c * 132 + t]);
        float sum = 0.f;
        for (int c = 0; c < OUTF; c++) sum += __expf(Os[c * 132 + t] - m);
        rowm[t] = m;
        rowls[t] = __logf(sum);
    }
    __syncthreads();
#pragma unroll
    for (int i = 0; i < 4; i++) {
        int row = rb + i;
        int gr = row0 + row;
        if (gr < NN) {
            float sh = rowm[row] + rowls[row];
            *(float4*)&outb[(size_t)gr * OUTF + cb] =
                make_float4(acc[i][0] - sh, acc[i][1] - sh,
                            acc[i][2] - sh, acc[i][3] - sh);
        }
    }
}

extern "C" void kernel_launch(void* const* d_in, const int* in_sizes, int n_in,
                              void* d_out, int out_size, void* d_ws, size_t ws_size,
                              hipStream_t stream) {
    const float* x  = (const float*)d_in[0];
    const int*   ei = (const int*)d_in[1];
    const float* W1 = (const float*)d_in[2];
    const float* b1 = (const float*)d_in[3];
    const float* W2 = (const float*)d_in[4];
    const float* b2 = (const float*)d_in[5];
    float* outb = (float*)d_out;

    // workspace layout (4B word units)
    float* dinv   = (float*)d_ws;                   // 100000
    int*   cursor = (int*)d_ws + 100000;            // 100000
    int*   bcnt   = (int*)d_ws + 200000;            // 512
    int*   eidx   = (int*)d_ws + 201024;            // 1600000
    u16*   h1     = (u16*)((int*)d_ws + 1801024);   // 6.4M bf16 = 3.2M words
    u16*   r      = (u16*)((int*)d_ws + 5001024);   // 6.4M bf16 = 3.2M words
    u16*   s      = (u16*)((int*)d_ws + 8201024);   // 6.4M bf16 = 3.2M words
    int*   bkt    = (int*)s;                        // NBKT*BCAPB = 2.0M words, dead before agg2

    k_zero<<<1, 512, 0, stream>>>(bcnt);
    k_bucket<<<NTILES, 512, 0, stream>>>(ei, bcnt, bkt);
    k_csr<<<NBKT, 256, 0, stream>>>(bcnt, bkt, dinv, cursor, eidx);

    // h1' = bf16((x@W1)*dinv)  -- MFMA
    k_gemm1<<<(NN + 63) / 64, 256, 0, stream>>>(x, W1, dinv, h1);
    // r' = bf16(relu(dinv*(sum h1') + b1) * dinv)  -- 2 nodes per wave, 4-deep
    k_agg<true><<<(NN / 2 * 64 + 255) / 256, 256, 0, stream>>>(cursor, eidx, dinv, h1, b1, r);
    // s = bf16(dinv*(sum r'))
    k_agg<false><<<(NN / 2 * 64 + 255) / 256, 256, 0, stream>>>(cursor, eidx, dinv, r, nullptr, s);
    // out = log_softmax(s @ W2 + b2)
    k_gemm2<<<(NN + 127) / 128, 320, 0, stream>>>(s, W2, b2, outb);
}

// Round 17
// 146.579 us; speedup vs baseline: 1.1216x; 1.1216x over previous
//
#include <hip/hip_runtime.h>
#include <math.h>

#define NN 100000
#define NE 1600000
#define F_IN 128
#define HID 64
#define OUTF 40
#define NBKT 391     // node buckets of 256 nodes
#define BCAPB 5120   // per-bucket capacity (mean 4096, +16 sigma)
#define TILE 8192    // edges per k_bucket block
#define NTILES 196   // ceil(NE/TILE)

typedef unsigned short u16;
typedef __attribute__((ext_vector_type(8))) __bf16 bf16x8;
typedef __attribute__((ext_vector_type(4))) float f32x4;

__device__ __forceinline__ u16 f2bf(float f) {  // RNE
    unsigned int x = __float_as_uint(f);
    return (u16)((x + 0x7fffu + ((x >> 16) & 1u)) >> 16);
}

// unpack int4 = 8 bf16, add into acc[8] (rows are pre-scaled by dinv -> pure add)
__device__ __forceinline__ void add8(const int4 v, float* acc) {
    acc[0] += __uint_as_float(((unsigned)v.x) << 16);
    acc[1] += __uint_as_float(v.x & 0xffff0000u);
    acc[2] += __uint_as_float(((unsigned)v.y) << 16);
    acc[3] += __uint_as_float(v.y & 0xffff0000u);
    acc[4] += __uint_as_float(((unsigned)v.z) << 16);
    acc[5] += __uint_as_float(v.z & 0xffff0000u);
    acc[6] += __uint_as_float(((unsigned)v.w) << 16);
    acc[7] += __uint_as_float(v.w & 0xffff0000u);
}

// ---------------- CSR build: LDS counting sort ----------------
__global__ void k_zero(int* bcnt) {
    int i = threadIdx.x;
    if (i < NBKT) bcnt[i] = 0;
}

__launch_bounds__(512)
__global__ void k_bucket(const int* __restrict__ ei, int* __restrict__ bcnt,
                         int* __restrict__ bkt) {
    __shared__ int hist[NBKT], goff[NBKT], cur[NBKT];
    __shared__ int ss[512];
    __shared__ int stage[TILE];
    int t = threadIdx.x;
    int e0 = blockIdx.x * TILE;
    int ecnt = min(TILE, NE - e0);
    if (t < NBKT) hist[t] = 0;
    __syncthreads();
    for (int i = t; i < ecnt; i += 512)
        atomicAdd(&hist[ei[NE + e0 + i] >> 8], 1);
    __syncthreads();
    // parallel exclusive scan over 391 bucket counts
    ss[t] = (t < NBKT) ? hist[t] : 0;
    __syncthreads();
    for (int o = 1; o < 512; o <<= 1) {
        int add = (t >= o) ? ss[t - o] : 0;
        __syncthreads();
        ss[t] += add;
        __syncthreads();
    }
    if (t < NBKT) cur[t] = ss[t] - hist[t];  // exclusive prefix
    if (t < NBKT) goff[t] = atomicAdd(&bcnt[t], hist[t]);
    __syncthreads();
    for (int i = t; i < ecnt; i += 512) {
        int c = ei[NE + e0 + i];
        int r = ei[e0 + i];
        int pos = atomicAdd(&cur[c >> 8], 1);
        stage[pos] = ((c & 255) << 17) | r;
    }
    __syncthreads();
    int wv = t >> 6, ln = t & 63;
    for (int b = wv; b < NBKT; b += 8) {
        int cnt = hist[b];
        int lo = cur[b] - cnt;
        int gb = b * BCAPB + goff[b];
        for (int i = ln; i < cnt; i += 64)
            bkt[gb + i] = stage[lo + i];
    }
}

// One block per bucket. Computes its own base = prefix(bcnt[0..b)) via
// masked block-reduce (k_scanb folded in).
__launch_bounds__(256)
__global__ void k_csr(const int* __restrict__ bcnt, const int* __restrict__ bkt,
                      float* __restrict__ dinv, int* __restrict__ cursor,
                      int* __restrict__ eidx) {
    __shared__ int hist[256], loff[256], cur[256], sscan[256];
    __shared__ int stage[BCAPB];
    int t = threadIdx.x;
    int b = blockIdx.x;
    // base = sum of bcnt[0..b)
    int v0 = (t < b) ? bcnt[t] : 0;
    int v1 = (t + 256 < b) ? bcnt[t + 256] : 0;
    sscan[t] = v0 + v1;
    __syncthreads();
    for (int o = 128; o > 0; o >>= 1) {
        if (t < o) sscan[t] += sscan[t + o];
        __syncthreads();
    }
    int base = sscan[0];
    int cnt = bcnt[b];
    const int* bp = bkt + b * BCAPB;
    hist[t] = 0;
    __syncthreads();
    for (int i = t; i < cnt; i += 256)
        atomicAdd(&hist[bp[i] >> 17], 1);
    __syncthreads();
    int n = b * 256 + t;
    int d = hist[t];
    if (n < NN) dinv[n] = rsqrtf((float)(d + 1));  // +1 self-loop
    sscan[t] = d;
    __syncthreads();
    for (int o = 1; o < 256; o <<= 1) {
        int add = (t >= o) ? sscan[t - o] : 0;
        __syncthreads();
        sscan[t] += add;
        __syncthreads();
    }
    loff[t] = sscan[t] - d;
    cur[t] = 0;
    if (n < NN) cursor[n] = base + sscan[t];  // rowoff[n+1]
    __syncthreads();
    for (int i = t; i < cnt; i += 256) {
        int v = bp[i];
        int pos = loff[v >> 17] + atomicAdd(&cur[v >> 17], 1);
        stage[pos] = v & 0x1FFFF;
    }
    __syncthreads();
    for (int i = t; i < cnt; i += 256)
        eidx[base + i] = stage[i];
}

// ---------------- GEMM1 (MFMA bf16): h1' = bf16((x @ W1) * dinv[row]) ----------------
__launch_bounds__(256)
__global__ void k_gemm1(const float* __restrict__ x, const float* __restrict__ W1,
                        const float* __restrict__ dinv, u16* __restrict__ h1) {
    __shared__ u16 Xs[64][136];   // bf16 x-tile, +8 pad
    __shared__ u16 Wt[64][136];   // bf16 W1^T [col][k]
    int t = threadIdx.x;
    int row0 = blockIdx.x * 64;

    for (int idx = t; idx < F_IN * HID; idx += 256)
        Wt[idx & 63][idx >> 6] = f2bf(W1[idx]);
#pragma unroll
    for (int i = 0; i < 8; i++) {
        int idx4 = t + 256 * i;
        int r = idx4 >> 5;
        int c4 = (idx4 & 31) << 2;
        int gr = row0 + r;
        if (gr >= NN) gr = NN - 1;
        float4 v = *(const float4*)&x[gr * F_IN + c4];
        ushort4 o;
        o.x = f2bf(v.x); o.y = f2bf(v.y); o.z = f2bf(v.z); o.w = f2bf(v.w);
        *(ushort4*)&Xs[r][c4] = o;
    }
    __syncthreads();

    int wave = t >> 6, lane = t & 63;
    int rloc = lane & 15;
    int koct = (lane >> 4) * 8;
    int wrow = wave * 16;

    f32x4 acc0 = {}, acc1 = {}, acc2 = {}, acc3 = {};
#pragma unroll
    for (int s = 0; s < 4; s++) {
        int k0 = s * 32 + koct;
        bf16x8 a = *(const bf16x8*)&Xs[wrow + rloc][k0];
        bf16x8 b0 = *(const bf16x8*)&Wt[rloc][k0];
        bf16x8 b1 = *(const bf16x8*)&Wt[16 + rloc][k0];
        bf16x8 b2 = *(const bf16x8*)&Wt[32 + rloc][k0];
        bf16x8 b3 = *(const bf16x8*)&Wt[48 + rloc][k0];
        acc0 = __builtin_amdgcn_mfma_f32_16x16x32_bf16(a, b0, acc0, 0, 0, 0);
        acc1 = __builtin_amdgcn_mfma_f32_16x16x32_bf16(a, b1, acc1, 0, 0, 0);
        acc2 = __builtin_amdgcn_mfma_f32_16x16x32_bf16(a, b2, acc2, 0, 0, 0);
        acc3 = __builtin_amdgcn_mfma_f32_16x16x32_bf16(a, b3, acc3, 0, 0, 0);
    }

    int rq = (lane >> 4) * 4;
#pragma unroll
    for (int i = 0; i < 4; i++) {
        int gr = row0 + wrow + rq + i;
        if (gr < NN) {
            float dn = dinv[gr];
            size_t base = (size_t)gr * HID + rloc;
            h1[base]      = f2bf(acc0[i] * dn);
            h1[base + 16] = f2bf(acc1[i] * dn);
            h1[base + 32] = f2bf(acc2[i] * dn);
            h1[base + 48] = f2bf(acc3[i] * dn);
        }
    }
}

// ---------------- aggregation: TWO nodes per wave, 2-deep (R12 proven) ----------------
// R16 lesson: guard the CONSUME, never the LOAD. Loads are unconditional with
// clamped index (lanes past m broadcast sidx=0 -> row 0, always valid); only
// add8 is guarded. 4-deep (R16) regressed: conditional loads + 48 VGPR.
template <bool RELU_BIAS>
__global__ void k_agg(const int* __restrict__ cursor, const int* __restrict__ eidx,
                      const float* __restrict__ dinv, const u16* __restrict__ h,
                      const float* __restrict__ bias, u16* __restrict__ outp) {
    int lane = threadIdx.x & 63;
    int wid = (blockIdx.x * blockDim.x + threadIdx.x) >> 6;
    int half = lane >> 5;
    int li = lane & 31;
    int n = wid * 2 + half;            // NN even, grid exact -> always < NN
    int eg = (lane >> 3) & 3;          // edge group 0..3 within half
    int fo = (lane & 7) * 8;           // 8 bf16 per lane
    int hbase = lane & 32;             // shfl base for this half
    int end = cursor[n];
    int start = (n == 0) ? 0 : cursor[n - 1];
    int deg = end - start;
    int degw = max(deg, __shfl_xor(deg, 32, 64));  // uniform loop bound

    float acc[8] = {}, acc2[8] = {};
    if (eg == 0) {  // self-loop row
        int4 hv = *(const int4*)&h[n * HID + fo];
        add8(hv, acc);
    }
    for (int c0 = 0; c0 < degw; c0 += 32) {
        int m = min(32, deg - c0);
        int mw = min(32, degw - c0);
        int sidx = (li < m) ? eidx[start + c0 + li] : 0;
        int kmax = (mw + 3) >> 2;
        int k = 0;
        for (; k + 2 <= kmax; k += 2) {
            int e0 = eg + (k << 2), e1 = e0 + 4;
            int s0 = __shfl(sidx, hbase + e0, 64);
            int s1 = __shfl(sidx, hbase + e1, 64);
            int4 a = *(const int4*)&h[s0 * HID + fo];   // unconditional, clamped
            int4 b = *(const int4*)&h[s1 * HID + fo];
            if (e0 < m) add8(a, acc);
            if (e1 < m) add8(b, acc2);
        }
        if (k < kmax) {
            int e0 = eg + (k << 2);
            int s0 = __shfl(sidx, hbase + e0, 64);
            int4 a = *(const int4*)&h[s0 * HID + fo];
            if (e0 < m) add8(a, acc);
        }
    }
#pragma unroll
    for (int i = 0; i < 8; i++) acc[i] += acc2[i];

    // reduce across the 4 edge groups of each half (lane bits 3,4)
#pragma unroll
    for (int o = 8; o <= 16; o <<= 1) {
#pragma unroll
        for (int i = 0; i < 8; i++) acc[i] += __shfl_xor(acc[i], o, 64);
    }
    if (eg == 0) {
        float dn = dinv[n];
        if (RELU_BIAS) {
#pragma unroll
            for (int i = 0; i < 8; i++)
                acc[i] = fmaxf(dn * acc[i] + bias[fo + i], 0.f) * dn;
        } else {
#pragma unroll
            for (int i = 0; i < 8; i++) acc[i] *= dn;
        }
        int4 o;
        o.x = (int)f2bf(acc[0]) | ((int)f2bf(acc[1]) << 16);
        o.y = (int)f2bf(acc[2]) | ((int)f2bf(acc[3]) << 16);
        o.z = (int)f2bf(acc[4]) | ((int)f2bf(acc[5]) << 16);
        o.w = (int)f2bf(acc[6]) | ((int)f2bf(acc[7]) << 16);
        *(int4*)&outp[(size_t)n * HID + fo] = o;
    }
}

// ---------------- GEMM2 (bf16 s) + bias + log_softmax fused ----------------
__launch_bounds__(320)
__global__ void k_gemm2(const u16* __restrict__ s_in, const float* __restrict__ W2,
                        const float* __restrict__ b2, float* __restrict__ outb) {
    __shared__ float As[128][68];   // staging; later reused as Os[40][132]
    __shared__ float Ws[64][40];
    __shared__ float rowm[128], rowls[128];
    int t = threadIdx.x;
    int row0 = blockIdx.x * 128;

    for (int i = t; i < 64 * 40; i += 320) Ws[i / 40][i % 40] = W2[i];

    for (int idx8 = t; idx8 < 1024; idx8 += 320) {
        int r = idx8 >> 3, k8 = (idx8 & 7) << 3;
        int gr = row0 + r;
        if (gr >= NN) gr = NN - 1;
        int4 v = *(const int4*)&s_in[(size_t)gr * HID + k8];
        float* dst = &As[r][k8];
        dst[0] = __uint_as_float(((unsigned)v.x) << 16);
        dst[1] = __uint_as_float(v.x & 0xffff0000u);
        dst[2] = __uint_as_float(((unsigned)v.y) << 16);
        dst[3] = __uint_as_float(v.y & 0xffff0000u);
        dst[4] = __uint_as_float(((unsigned)v.z) << 16);
        dst[5] = __uint_as_float(v.z & 0xffff0000u);
        dst[6] = __uint_as_float(((unsigned)v.w) << 16);
        dst[7] = __uint_as_float(v.w & 0xffff0000u);
    }
    __syncthreads();

    int tx = t % 10, ty = t / 10;
    int cb = tx * 4, rb = ty * 4;
    float acc[4][4] = {};
#pragma unroll 2   // capped: full unroll spills (R1)
    for (int k = 0; k < HID; k += 4) {
        float4 xv[4], wv[4];
#pragma unroll
        for (int i = 0; i < 4; i++) xv[i] = *(const float4*)&As[rb + i][k];
#pragma unroll
        for (int kk = 0; kk < 4; kk++) wv[kk] = *(const float4*)&Ws[k + kk][cb];
#pragma unroll
        for (int i = 0; i < 4; i++) {
            const float* xp = (const float*)&xv[i];
#pragma unroll
            for (int kk = 0; kk < 4; kk++) {
                acc[i][0] += xp[kk] * wv[kk].x;
                acc[i][1] += xp[kk] * wv[kk].y;
                acc[i][2] += xp[kk] * wv[kk].z;
                acc[i][3] += xp[kk] * wv[kk].w;
            }
        }
    }
    float4 bb = *(const float4*)&b2[cb];
#pragma unroll
    for (int i = 0; i < 4; i++) {
        acc[i][0] += bb.x; acc[i][1] += bb.y;
        acc[i][2] += bb.z; acc[i][3] += bb.w;
    }

    __syncthreads();  // all As reads done; reuse as Os[40][132]
    float* Os = &As[0][0];
#pragma unroll
    for (int i = 0; i < 4; i++) {
        int row = rb + i;
        Os[(cb + 0) * 132 + row] = acc[i][0];
        Os[(cb + 1) * 132 + row] = acc[i][1];
        Os[(cb + 2) * 132 + row] = acc[i][2];
        Os[(cb + 3) * 132 + row] = acc[i][3];
    }
    __syncthreads();
    if (t < 128) {
        float m = -INFINITY;
        for (int c = 0; c < OUTF; c++) m = fmaxf(m, Os[c * 132 + t]);
        float sum = 0.f;
        for (int c = 0; c < OUTF; c++) sum += __expf(Os[c * 132 + t] - m);
        rowm[t] = m;
        rowls[t] = __logf(sum);
    }
    __syncthreads();
#pragma unroll
    for (int i = 0; i < 4; i++) {
        int row = rb + i;
        int gr = row0 + row;
        if (gr < NN) {
            float sh = rowm[row] + rowls[row];
            *(float4*)&outb[(size_t)gr * OUTF + cb] =
                make_float4(acc[i][0] - sh, acc[i][1] - sh,
                            acc[i][2] - sh, acc[i][3] - sh);
        }
    }
}

extern "C" void kernel_launch(void* const* d_in, const int* in_sizes, int n_in,
                              void* d_out, int out_size, void* d_ws, size_t ws_size,
                              hipStream_t stream) {
    const float* x  = (const float*)d_in[0];
    const int*   ei = (const int*)d_in[1];
    const float* W1 = (const float*)d_in[2];
    const float* b1 = (const float*)d_in[3];
    const float* W2 = (const float*)d_in[4];
    const float* b2 = (const float*)d_in[5];
    float* outb = (float*)d_out;

    // workspace layout (4B word units)
    float* dinv   = (float*)d_ws;                   // 100000
    int*   cursor = (int*)d_ws + 100000;            // 100000
    int*   bcnt   = (int*)d_ws + 200000;            // 512
    int*   eidx   = (int*)d_ws + 201024;            // 1600000
    u16*   h1     = (u16*)((int*)d_ws + 1801024);   // 6.4M bf16 = 3.2M words
    u16*   r      = (u16*)((int*)d_ws + 5001024);   // 6.4M bf16 = 3.2M words
    u16*   s      = (u16*)((int*)d_ws + 8201024);   // 6.4M bf16 = 3.2M words
    int*   bkt    = (int*)s;                        // NBKT*BCAPB = 2.0M words, dead before agg2

    k_zero<<<1, 512, 0, stream>>>(bcnt);
    k_bucket<<<NTILES, 512, 0, stream>>>(ei, bcnt, bkt);
    k_csr<<<NBKT, 256, 0, stream>>>(bcnt, bkt, dinv, cursor, eidx);

    // h1' = bf16((x@W1)*dinv)  -- MFMA
    k_gemm1<<<(NN + 63) / 64, 256, 0, stream>>>(x, W1, dinv, h1);
    // r' = bf16(relu(dinv*(sum h1') + b1) * dinv)  -- 2 nodes/wave, 2-deep
    k_agg<true><<<(NN / 2 * 64 + 255) / 256, 256, 0, stream>>>(cursor, eidx, dinv, h1, b1, r);
    // s = bf16(dinv*(sum r'))
    k_agg<false><<<(NN / 2 * 64 + 255) / 256, 256, 0, stream>>>(cursor, eidx, dinv, r, nullptr, s);
    // out = log_softmax(s @ W2 + b2)
    k_gemm2<<<(NN + 127) / 128, 320, 0, stream>>>(s, W2, b2, outb);
}